// Round 10
// baseline (1241.985 us; speedup 1.0000x reference)
//
#include <hip/hip_runtime.h>

// LSTM B=512 T=1024 H=150 I=1 + Linear(150->1) + sigmoid.
// 32 blocks x 256 threads (4 waves, 1/SIMD). Block owns 16 sequences.
// ROUND-10: round-9 redo (compile fix only: cvt_pkrtz returns __fp16x2).
//  - Cell-pair remap: tile pair P=(2a,2a+1) maps lane (q,j) -> cell 8a+2q+p,
//    gate j. Each lane owns cells (2k,2k+1) -> h written as ONE packed
//    ds_write_b32 (cvt_pkrtz). Old b16 writes had 2-lanes-same-dword
//    serialization = the 7.7M SQ_LDS_BANK_CONFLICT. New pattern: bank =
//    (20b+8P+q)%32 -> exact 2-way = free.
//  - 4 waves: LDS panel reads halve (20 ds_read_b128/step/CU). Per-SIMD
//    trans/VALU/MFMA totals unchanged (invariant across r3-r8).
//  - waves_per_eu(1,1): 512-reg budget; wave holds up to 10 tiles of weights
//    (wf 200 regs) without spill.
//  - Out row rides pair 18 (tile 37, r=12..15 slot, j=0).
// K = 160: k<150 = h, k=150 = 1.0 (bias), k=151 = x_t, rest 0.
// Weights pre-scaled by -log2e (i,f,o,out) / +2log2e (g); c-state stored
// pre-scaled by 2log2e so ec = exp2(cst) directly. 5 exp2 + 2 rcp per cell.

typedef _Float16 half8 __attribute__((ext_vector_type(8)));
typedef __fp16 fp16x2 __attribute__((ext_vector_type(2)));
typedef float f32x4 __attribute__((ext_vector_type(4)));

#define LOG2E 1.44269504088896340736f
#define TWOLOG2E 2.88539008177792681472f

// pointwise for one cell: gates in ACC (f32x4: i',f',g',o' pre-scaled), state CST
#define PW_CELL(ACC, CST, HOUT)                                              \
  {                                                                          \
    const float ei = __builtin_amdgcn_exp2f(ACC[0]);                         \
    const float ef = __builtin_amdgcn_exp2f(ACC[1]);                         \
    const float eg = __builtin_amdgcn_exp2f(ACC[2]);                         \
    const float eo = __builtin_amdgcn_exp2f(ACC[3]);                         \
    const float A   = 1.0f + ei;                      /* 1/i */              \
    const float F   = 1.0f + ef;                      /* 1/f */              \
    const float G1  = eg + 1.0f;                                             \
    const float Gm2 = fmaf(eg, TWOLOG2E, -TWOLOG2E);  /* 2log2e*(eg-1) */    \
    const float AG  = A * G1;                                                \
    const float num = fmaf(CST, AG, Gm2 * F);         /* CST = 2log2e*c */   \
    CST = num * __builtin_amdgcn_rcpf(F * AG);                               \
    const float ec = __builtin_amdgcn_exp2f(CST);                            \
    HOUT = (ec - 1.0f) *                                                     \
           __builtin_amdgcn_rcpf((1.0f + eo) * (ec + 1.0f)); /* o*tanh(c) */ \
  }

__global__
__attribute__((amdgpu_flat_work_group_size(256, 256), amdgpu_waves_per_eu(1, 1)))
void lstm_kernel(
    const float* __restrict__ x,      // [512][1024]
    const float* __restrict__ W_ih,   // [600]
    const float* __restrict__ W_hh,   // [600][150]
    const float* __restrict__ b_ih,   // [600]
    const float* __restrict__ b_hh,   // [600]
    const float* __restrict__ W_out,  // [150]
    const float* __restrict__ b_out,  // [1]
    float* __restrict__ out)          // [512][1024]
{
  const int tid  = threadIdx.x;
  const int wid  = tid >> 6;
  const int lane = tid & 63;
  const int q    = lane >> 4;   // k-subchunk for A/B frags; cell-pair selector for D
  const int b    = lane & 15;   // batch col (B/D); A-frag row m
  const int bid  = blockIdx.x;

  // stride 168 f16 = 84 dwords (== 20 mod 32): b128 panel reads are uniform
  // 8/bank (the b128 minimum); packed b32 h-writes are exact 2-way (free).
  __shared__ __align__(16) _Float16 hbuf[2][16][168];
  __shared__ _Float16 xlds[16][1032];

  // ---- prologue: zero hbuf, stage x as f16 ----
  for (int i = tid; i < 2*16*168; i += 256)
    (&hbuf[0][0][0])[i] = (_Float16)0.0f;
  {
    const float4* x4 = (const float4*)(x + (size_t)bid * 16 * 1024);
    for (int i = tid; i < 16*256; i += 256) {
      int row = i >> 8, c4 = i & 255;
      float4 v = x4[row*256 + c4];
      xlds[row][c4*4+0] = (_Float16)v.x;
      xlds[row][c4*4+1] = (_Float16)v.y;
      xlds[row][c4*4+2] = (_Float16)v.z;
      xlds[row][c4*4+3] = (_Float16)v.w;
    }
  }
  __syncthreads();
  if (tid < 32) hbuf[tid>>4][tid&15][150] = (_Float16)1.0f;  // bias column
  if (tid < 16) hbuf[0][tid][151] = xlds[tid][0];            // x_0
  __syncthreads();

  // ---- pair ownership: wave w -> pairs [5w, 5w+np); w3 has 4 (15..18) ----
  const int np = (wid < 3) ? 5 : 4;

  // ---- weight fragments: wf[pair][p][chunk], up to 5x2x5 half8 = 200 VGPR ----
  const float bo = b_out[0];
  half8 wf[5][2][5];
#pragma unroll
  for (int pr = 0; pr < 5; ++pr) {
    const int P = wid*5 + pr;          // global pair
#pragma unroll
    for (int p = 0; p < 2; ++p) {
#pragma unroll
      for (int s = 0; s < 5; ++s) wf[pr][p][s] = (half8)(_Float16)0.0f;
      if (pr < np) {
        // A-frag row r = b; cell = 8P + 2*(r>>2) + p, gate = r&3
        const int cell = 8*P + 2*(b >> 2) + p;
        const int gate = b & 3;
        const bool outrow = (P == 18) && (p == 1) && ((b >> 2) == 3) && (gate == 0);
        const float alpha = (gate == 2) ? TWOLOG2E : -LOG2E;
#pragma unroll
        for (int s = 0; s < 5; ++s) {
          half8 v;
#pragma unroll
          for (int j = 0; j < 8; ++j) {
            const int k = s*32 + q*8 + j;   // same (q,j)->k map as B frags
            float w = 0.0f;
            if (outrow) {
              if (k < 150)       w = -LOG2E * W_out[k];
              else if (k == 150) w = -LOG2E * bo;
            } else if (cell < 150) {
              const int orow = gate*150 + cell;
              if (k < 150)       w = alpha * W_hh[orow*150 + k];
              else if (k == 150) w = alpha * (b_ih[orow] + b_hh[orow]);
              else if (k == 151) w = alpha * W_ih[orow];
            }
            v[j] = (_Float16)w;
          }
          wf[pr][p][s] = v;
        }
      }
    }
  }

  // c-state (pre-scaled by 2log2e), per pair: even/odd cell
  float cstE[5] = {0.f,0.f,0.f,0.f,0.f};
  float cstO[5] = {0.f,0.f,0.f,0.f,0.f};

  const bool is_x   = (wid == 3) && (q == 1);
  const bool is_out = (wid == 3) && (q == 3);  // pair18 odd, reg 0
  float* outp = out + ((size_t)bid*16 + b) * 1024;

  // precomputed LDS addresses (constant offsets per step -> cndmask select)
  const _Float16* rb[2] = { &hbuf[0][b][q*8], &hbuf[1][b][q*8] };
  _Float16* wp[2][5];
#pragma unroll
  for (int pr = 0; pr < 5; ++pr) {
    const int cell0 = 8*(wid*5 + pr) + 2*q;
    wp[0][pr] = &hbuf[0][b][cell0 < 152 ? cell0 : 152];  // clamp junk (guarded)
    wp[1][pr] = &hbuf[1][b][cell0 < 152 ? cell0 : 152];
  }

  int cur = 0;
  for (int t = 0; t <= 1024; ++t) {
    _Float16 xv = (_Float16)0.0f;
    if (is_x && t < 1023) xv = xlds[b][t+1];   // issued early, used post-pointwise

    const _Float16* r0 = rb[cur];
    half8 bf[5];
#pragma unroll
    for (int s = 0; s < 5; ++s)
      bf[s] = *(const half8*)(r0 + s*32);

    f32x4 accE[5], accO[5];
#pragma unroll
    for (int pr = 0; pr < 5; ++pr) {
      if (pr < np) {
        f32x4 ae = {0.f,0.f,0.f,0.f}, ao = {0.f,0.f,0.f,0.f};
#pragma unroll
        for (int s = 0; s < 5; ++s) {
          ae = __builtin_amdgcn_mfma_f32_16x16x32_f16(wf[pr][0][s], bf[s], ae, 0,0,0);
          ao = __builtin_amdgcn_mfma_f32_16x16x32_f16(wf[pr][1][s], bf[s], ao, 0,0,0);
        }
        accE[pr] = ae; accO[pr] = ao;
      }
    }

    // out_{t-1} = sigmoid(Wout.h_{t-1} + b_out); rides pair18-odd reg 0
    if (is_out && t >= 1)
      outp[t-1] = __builtin_amdgcn_rcpf(1.0f + __builtin_amdgcn_exp2f(accO[3][0]));
    if (t == 1024) break;

    const int nxt = cur ^ 1;
#pragma unroll
    for (int pr = 0; pr < 5; ++pr) {
      if (pr < np) {
        float hE, hO;
        PW_CELL(accE[pr], cstE[pr], hE);
        PW_CELL(accO[pr], cstO[pr], hO);
        const int P = wid*5 + pr;
        if (P < 18 || q < 3) {               // skip fake cells 150/151 slot
          fp16x2 hv = __builtin_amdgcn_cvt_pkrtz(hE, hO);
          *(fp16x2*)wp[nxt][pr] = hv;        // packed b32, 2-way banks (free)
        }
      }
    }
    if (is_x && t < 1023) hbuf[nxt][b][151] = xv;  // x_{t+1}
    __syncthreads();
    cur = nxt;
  }
}

extern "C" void kernel_launch(void* const* d_in, const int* in_sizes, int n_in,
                              void* d_out, int out_size, void* d_ws, size_t ws_size,
                              hipStream_t stream) {
  const float* x     = (const float*)d_in[0];
  const float* W_ih  = (const float*)d_in[1];
  const float* W_hh  = (const float*)d_in[2];
  const float* b_ih  = (const float*)d_in[3];
  const float* b_hh  = (const float*)d_in[4];
  const float* W_out = (const float*)d_in[5];
  const float* b_out = (const float*)d_in[6];
  lstm_kernel<<<dim3(32), dim3(256), 0, stream>>>(
      x, W_ih, W_hh, b_ih, b_hh, W_out, b_out, (float*)d_out);
}

// Round 11
// 867.974 us; speedup vs baseline: 1.4309x; 1.4309x over previous
//
#include <hip/hip_runtime.h>

// LSTM B=512 T=1024 H=150 I=1 + Linear(150->1) + sigmoid.
// ROUND-11: 64 blocks x 8 seqs, PW pair-merge via batch duplication.
//   r1-r10 invariance (waves/VGPR/barriers/skew/conflicts all null) leaves
//   VALU+trans wave-instruction count as the biggest reducible term:
//   trans instrs/SIMD = tiles/SIMD x 7 (lane-packing already optimal at 16
//   seqs). Fix: 8 seqs/block (64 blocks), lane b reads h-row b&7 -> MFMA D
//   lanes b>=8 duplicate batch b-8 -> tile pair (p, p+19) merges with 4
//   cndmasks into one full PW wave: trans instrs HALVE per CU. MFMA count
//   unchanged (matrix pipe ~25% busy). 12 waves (r6-best), 1 block/CU pad.
// M = 640 vrows (4*cell+gate), 38 tiles; vrow 600 = W_out ride-along.
// K = 160: k<150 = h (LDS, dbuf), k=150 = 1.0 (bias), k=151 = x_t.
// Weights pre-scaled by -log2e / +2log2e: PW = 5 exp2 + 2 rcp per cell.

typedef _Float16 half8 __attribute__((ext_vector_type(8)));
typedef float f32x4 __attribute__((ext_vector_type(4)));

#define LOG2E 1.44269504088896340736f
#define TWOLOG2E 2.88539008177792681472f

__global__
__attribute__((amdgpu_flat_work_group_size(768, 768), amdgpu_waves_per_eu(3, 3)))
void lstm_kernel(
    const float* __restrict__ x,      // [512][1024]
    const float* __restrict__ W_ih,   // [600]
    const float* __restrict__ W_hh,   // [600][150]
    const float* __restrict__ b_ih,   // [600]
    const float* __restrict__ b_hh,   // [600]
    const float* __restrict__ W_out,  // [150]
    const float* __restrict__ b_out,  // [1]
    float* __restrict__ out)          // [512][1024]
{
  const int tid  = threadIdx.x;
  const int wid  = tid >> 6;
  const int lane = tid & 63;
  const int q    = lane >> 4;   // k-subchunk for A/B frags; cell offset for D
  const int b    = lane & 15;   // D col; A-frag row m
  const int br   = b & 7;       // real batch (rows 8-15 duplicate 0-7)
  const int bid  = blockIdx.x;

  __shared__ __align__(16) _Float16 hbuf[2][8][168];
  // cols 0-1023 hold x; rest pads LDS to 82.2KB -> 1 block/CU.
  __shared__ _Float16 xlds[8][4800];

  // ---- prologue: zero hbuf, stage this block's 8 sequences of x ----
  for (int i = tid; i < 2*8*168; i += 768)
    (&hbuf[0][0][0])[i] = (_Float16)0.0f;
  {
    const float4* x4 = (const float4*)(x + (size_t)bid * 8 * 1024);
    for (int i = tid; i < 8*256; i += 768) {
      int row = i >> 8, c4 = i & 255;
      float4 v = x4[row*256 + c4];
      xlds[row][c4*4+0] = (_Float16)v.x;
      xlds[row][c4*4+1] = (_Float16)v.y;
      xlds[row][c4*4+2] = (_Float16)v.z;
      xlds[row][c4*4+3] = (_Float16)v.w;
    }
  }
  __syncthreads();
  if (tid < 16) hbuf[tid>>3][tid&7][150] = (_Float16)1.0f;  // bias col, both bufs
  if (tid < 8)  hbuf[0][tid][151] = xlds[tid][0];           // x_0
  __syncthreads();

  // ---- pair ownership: wave w -> pairs {w, 12+w (if w<7)}; pair p = tiles (p, p+19) ----
  const int npr = (wid < 7) ? 2 : 1;
  int prs[2];
  prs[0] = wid; prs[1] = 12 + wid;

  // ---- weight fragments: wf[pair][half][chunk], <= 2x2x5 half8 = 80 VGPR ----
  const float bo = b_out[0];
  half8 wf[2][2][5];
#pragma unroll
  for (int pr = 0; pr < 2; ++pr) {
#pragma unroll
    for (int hf = 0; hf < 2; ++hf) {
#pragma unroll
      for (int s = 0; s < 5; ++s) wf[pr][hf][s] = (half8)(_Float16)0.0f;
      if (pr < npr) {
        const int tg   = prs[pr] + 19*hf;
        const int vrow = tg*16 + b;          // A-frag: m = lane&15
        const int cell = vrow >> 2, gate = vrow & 3;
        const float alpha = (gate == 2) ? TWOLOG2E : -LOG2E;
#pragma unroll
        for (int s = 0; s < 5; ++s) {
          half8 v;
#pragma unroll
          for (int j = 0; j < 8; ++j) {
            const int k = s*32 + q*8 + j;    // same (q,j)->k map as B frags
            float w = 0.0f;
            if (vrow == 600) {               // out row
              if (k < 150)       w = -LOG2E * W_out[k];
              else if (k == 150) w = -LOG2E * bo;
            } else if (cell < 150) {
              const int orow = gate*150 + cell;
              if (k < 150)       w = alpha * W_hh[orow*150 + k];
              else if (k == 150) w = alpha * (b_ih[orow] + b_hh[orow]);
              else if (k == 151) w = alpha * W_ih[orow];
            }
            v[j] = (_Float16)w;
          }
          wf[pr][hf][s] = v;
        }
      }
    }
  }

  float cst[2] = {0.f, 0.f};     // merged-lane c state (one cell per lane per pair)
  const bool blo    = (b < 8);
  const bool is_x   = (wid == 11) && (q == 3) && blo;
  const bool is_out = (wid == 6)  && (q == 2) && !blo;  // pair 18 second tile, reg 0
  float* outp = out + ((size_t)bid*8 + br) * 1024;

  // precomputed merged write targets: lane -> (cell, batch br)
  _Float16* wp[2][2];
  bool wen[2];
#pragma unroll
  for (int pr = 0; pr < 2; ++pr) {
    const int p = prs[pr];
    const int wcell = blo ? (4*p + q) : (4*(p + 19) + q);
    wen[pr] = (pr < npr) && (wcell < 150);
    const int wc = (wcell < 150) ? wcell : 152;  // clamped; writes are guarded
    wp[0][pr] = &hbuf[0][br][wc];
    wp[1][pr] = &hbuf[1][br][wc];
  }
  const _Float16* rb[2] = { &hbuf[0][br][q*8], &hbuf[1][br][q*8] };

  int cur = 0;
  for (int t = 0; t <= 1024; ++t) {
    _Float16 xv = (_Float16)0.0f;
    if (is_x && t < 1023) xv = xlds[br][t+1];  // issued early, used post-pointwise

    const _Float16* r0 = rb[cur];
    half8 bf[5];
#pragma unroll
    for (int s = 0; s < 5; ++s)
      bf[s] = *(const half8*)(r0 + s*32);

    f32x4 accA[2], accB[2];
#pragma unroll
    for (int pr = 0; pr < 2; ++pr) {
      if (pr < npr) {
        f32x4 a = {0.f,0.f,0.f,0.f}, c = {0.f,0.f,0.f,0.f};
#pragma unroll
        for (int s = 0; s < 5; ++s) {
          a = __builtin_amdgcn_mfma_f32_16x16x32_f16(wf[pr][0][s], bf[s], a, 0,0,0);
          c = __builtin_amdgcn_mfma_f32_16x16x32_f16(wf[pr][1][s], bf[s], c, 0,0,0);
        }
        accA[pr] = a; accB[pr] = c;
      }
    }

    // out_{t-1} = sigmoid(Wout.h_{t-1} + b_out); tile 37 = pair-18 second half
    if (is_out && t >= 1)
      outp[t-1] = __builtin_amdgcn_rcpf(1.0f + __builtin_amdgcn_exp2f(accB[1][0]));
    if (t == 1024) break;

    const int nxt = cur ^ 1;
#pragma unroll
    for (int pr = 0; pr < 2; ++pr) {
      if (pr < npr) {
        // merge: lanes b<8 = first tile's gates, b>=8 = second tile's (batch b-8
        // duplication makes lanes b>=8 of accB hold exactly that tile's gates)
        f32x4 g;
#pragma unroll
        for (int r = 0; r < 4; ++r)
          g[r] = blo ? accA[pr][r] : accB[pr][r];
        // acc regs: 0=i',1=f',2=g',3=o' (pre-scaled preacts)
        const float ei = __builtin_amdgcn_exp2f(g[0]);
        const float ef = __builtin_amdgcn_exp2f(g[1]);
        const float eg = __builtin_amdgcn_exp2f(g[2]);
        const float eo = __builtin_amdgcn_exp2f(g[3]);
        const float A   = 1.0f + ei;     // 1/i
        const float F   = 1.0f + ef;     // 1/f
        const float G1  = eg + 1.0f;
        const float Gm  = eg - 1.0f;     // g = Gm/G1
        const float AG  = A * G1;
        const float num = fmaf(cst[pr], AG, Gm * F);
        const float cn  = num * __builtin_amdgcn_rcpf(F * AG);
        cst[pr] = cn;
        const float ec = __builtin_amdgcn_exp2f(TWOLOG2E * cn);
        const float hv = (ec - 1.0f) *
                         __builtin_amdgcn_rcpf((1.0f + eo) * (ec + 1.0f)); // o*tanh(c)
        if (wen[pr]) *wp[nxt][pr] = (_Float16)hv;
      }
    }
    if (is_x && t < 1023) hbuf[nxt][br][151] = xv;  // x_{t+1}
    __syncthreads();
    cur = nxt;
  }
}

extern "C" void kernel_launch(void* const* d_in, const int* in_sizes, int n_in,
                              void* d_out, int out_size, void* d_ws, size_t ws_size,
                              hipStream_t stream) {
  const float* x     = (const float*)d_in[0];
  const float* W_ih  = (const float*)d_in[1];
  const float* W_hh  = (const float*)d_in[2];
  const float* b_ih  = (const float*)d_in[3];
  const float* b_hh  = (const float*)d_in[4];
  const float* W_out = (const float*)d_in[5];
  const float* b_out = (const float*)d_in[6];
  lstm_kernel<<<dim3(64), dim3(768), 0, stream>>>(
      x, W_ih, W_hh, b_ih, b_hh, W_out, b_out, (float*)d_out);
}

// Round 12
// 853.627 us; speedup vs baseline: 1.4550x; 1.0168x over previous
//
#include <hip/hip_runtime.h>

// LSTM B=512 T=1024 H=150 I=1 + Linear(150->1) + sigmoid.
// ROUND-12: extend r11's winning lever (PW issue-work reduction) 3 ways:
//  - 128 blocks x 4 seqs: lane b reads h-row b&3 -> MFMA D duplicates 4x ->
//    tile QUAD (4p..4p+3) merges into one PW wave (12 cndmasks). Trans and
//    PW-VALU per CU halve again vs r11.
//  - 8 waves (512 thr): LDS panel reads 60->40 b128/CU/step (was 720 cyc).
//    Quads: waves 0-5 own 1, waves 6,7 own 2 (10 quads; SIMDs 2,2,3,3).
//  - stride 176 f16 (88 dw): read bank = (24br+4q+w)%32 = uniform 2-way
//    (free); write dwords hit 32 distinct banks. r11's 168-stride at 8 rows
//    was ~3-way = the 16.2M SQ_LDS_BANK_CONFLICT.
// M = 640 vrows (4*cell+gate), 38 tiles; vrow 600 = W_out ride-along.
// K = 160: k<150 = h (LDS dbuf), k=150 = 1.0 (bias), k=151 = x_t.
// Weights pre-scaled by -log2e / +2log2e: PW = 5 exp2 + 2 rcp per cell.
// xlds oversized to keep LDS > 80KB -> 1 block/CU -> 2-waves/EU reg budget.

typedef _Float16 half8 __attribute__((ext_vector_type(8)));
typedef float f32x4 __attribute__((ext_vector_type(4)));

#define LOG2E 1.44269504088896340736f
#define TWOLOG2E 2.88539008177792681472f

__global__
__attribute__((amdgpu_flat_work_group_size(512, 512), amdgpu_waves_per_eu(2, 2)))
void lstm_kernel(
    const float* __restrict__ x,      // [512][1024]
    const float* __restrict__ W_ih,   // [600]
    const float* __restrict__ W_hh,   // [600][150]
    const float* __restrict__ b_ih,   // [600]
    const float* __restrict__ b_hh,   // [600]
    const float* __restrict__ W_out,  // [150]
    const float* __restrict__ b_out,  // [1]
    float* __restrict__ out)          // [512][1024]
{
  const int tid  = threadIdx.x;
  const int wid  = tid >> 6;
  const int lane = tid & 63;
  const int q    = lane >> 4;   // k-subchunk for A/B frags; cell offset for D
  const int b    = lane & 15;   // D col; A-frag row m
  const int br   = b & 3;       // real batch (cols duplicate mod 4)
  const int e    = b >> 2;      // tile-within-quad selector for PW merge
  const int bid  = blockIdx.x;

  // stride 176 f16 = 88 dwords: 24br+4q read pattern = uniform 2-way (free)
  __shared__ __align__(16) _Float16 hbuf[2][4][176];
  // cols 0-1023 hold x; oversized to pad LDS >80KB (1 block/CU).
  __shared__ _Float16 xlds[4][10240];

  // ---- prologue: zero hbuf, stage this block's 4 sequences of x ----
  for (int i = tid; i < 2*4*176; i += 512)
    (&hbuf[0][0][0])[i] = (_Float16)0.0f;
  {
    const float4* x4 = (const float4*)(x + (size_t)bid * 4 * 1024);
    for (int i = tid; i < 4*256; i += 512) {
      int row = i >> 8, c4 = i & 255;
      float4 v = x4[row*256 + c4];
      xlds[row][c4*4+0] = (_Float16)v.x;
      xlds[row][c4*4+1] = (_Float16)v.y;
      xlds[row][c4*4+2] = (_Float16)v.z;
      xlds[row][c4*4+3] = (_Float16)v.w;
    }
  }
  __syncthreads();
  if (tid < 8) hbuf[tid>>2][tid&3][150] = (_Float16)1.0f;  // bias col, both bufs
  if (tid < 4) hbuf[0][tid][151] = xlds[tid][0];           // x_0
  __syncthreads();

  // ---- quad ownership: waves 0-5 -> {w}; wave 6 -> {6,8}; wave 7 -> {7,9} ----
  const int nq = (wid >= 6) ? 2 : 1;
  int quads[2];
  quads[0] = wid;
  quads[1] = (wid == 6) ? 8 : 9;

  // ---- weight fragments: wf[quad][tile][chunk] <= 2x4x5 half8 = 160 VGPR ----
  const float bo = b_out[0];
  half8 wf[2][4][5];
#pragma unroll
  for (int qq = 0; qq < 2; ++qq) {
#pragma unroll
    for (int tl = 0; tl < 4; ++tl) {
#pragma unroll
      for (int s = 0; s < 5; ++s) wf[qq][tl][s] = (half8)(_Float16)0.0f;
      const int tg = quads[qq]*4 + tl;
      if (qq < nq && tg < 38) {
        const int vrow = tg*16 + b;          // A-frag: m = lane&15
        const int cell = vrow >> 2, gate = vrow & 3;
        const float alpha = (gate == 2) ? TWOLOG2E : -LOG2E;
#pragma unroll
        for (int s = 0; s < 5; ++s) {
          half8 v;
#pragma unroll
          for (int j = 0; j < 8; ++j) {
            const int k = s*32 + q*8 + j;    // same (q,j)->k map as B frags
            float w = 0.0f;
            if (vrow == 600) {               // out row
              if (k < 150)       w = -LOG2E * W_out[k];
              else if (k == 150) w = -LOG2E * bo;
            } else if (cell < 150) {
              const int orow = gate*150 + cell;
              if (k < 150)       w = alpha * W_hh[orow*150 + k];
              else if (k == 150) w = alpha * (b_ih[orow] + b_hh[orow]);
              else if (k == 151) w = alpha * W_ih[orow];
            }
            v[j] = (_Float16)w;
          }
          wf[qq][tl][s] = v;
        }
      }
    }
  }

  float cst[2] = {0.f, 0.f};     // merged-lane c state (one cell per lane per quad)
  const bool is_x   = (wid == 5) && (q == 3) && (b < 4);
  const bool is_out = (wid == 7) && (q == 2) && (b < 4);  // tile37 row8: q=2,reg0
  float* outp = out + ((size_t)bid*4 + br) * 1024;

  // precomputed LDS pointers (static per buffer -> cndmask select on cur/nxt)
  const _Float16* rb0 = &hbuf[0][br][q*8];
  const _Float16* rb1 = &hbuf[1][br][q*8];
  _Float16 *wp0[2], *wp1[2];
  bool wen[2];
#pragma unroll
  for (int qq = 0; qq < 2; ++qq) {
    const int cell = quads[qq]*16 + 4*e + q;   // merged lane -> cell
    wen[qq] = (qq < nq) && (cell < 150);
    const int wc = (cell < 150) ? cell : 152;  // clamp into junk col (guarded)
    wp0[qq] = &hbuf[0][br][wc];
    wp1[qq] = &hbuf[1][br][wc];
  }

  int cur = 0;
  for (int t = 0; t <= 1024; ++t) {
    _Float16 xv = (_Float16)0.0f;
    if (is_x && t < 1023) xv = xlds[b][t+1];   // issued early, used post-PW

    const _Float16* r0 = cur ? rb1 : rb0;
    half8 bf[5];
#pragma unroll
    for (int s = 0; s < 5; ++s)
      bf[s] = *(const half8*)(r0 + s*32);

    f32x4 acc[2][4];
#pragma unroll
    for (int qq = 0; qq < 2; ++qq) {
      if (qq < nq) {
#pragma unroll
        for (int tl = 0; tl < 4; ++tl) {
          f32x4 a = {0.f, 0.f, 0.f, 0.f};
#pragma unroll
          for (int s = 0; s < 5; ++s)
            a = __builtin_amdgcn_mfma_f32_16x16x32_f16(wf[qq][tl][s], bf[s], a, 0,0,0);
          acc[qq][tl] = a;
        }
      }
    }

    // out_{t-1} = sigmoid(Wout.h_{t-1}+b_out): wave7 qq=1 tl=1 (tile 37), reg 0
    if (is_out && t >= 1)
      outp[t-1] = __builtin_amdgcn_rcpf(1.0f + __builtin_amdgcn_exp2f(acc[1][1][0]));
    if (t == 1024) break;

    const int nxt = cur ^ 1;
#pragma unroll
    for (int qq = 0; qq < 2; ++qq) {
      if (qq < nq) {
        // 4-way merge: lane group e = b>>2 takes tile 4*quad+e's gates
        const bool s1 = (b & 4) != 0, s2 = (b & 8) != 0;
        f32x4 g;
#pragma unroll
        for (int r = 0; r < 4; ++r) {
          const float v01 = s1 ? acc[qq][1][r] : acc[qq][0][r];
          const float v23 = s1 ? acc[qq][3][r] : acc[qq][2][r];
          g[r] = s2 ? v23 : v01;
        }
        // g: 0=i',1=f',2=g',3=o' (pre-scaled preacts)
        const float ei = __builtin_amdgcn_exp2f(g[0]);
        const float ef = __builtin_amdgcn_exp2f(g[1]);
        const float eg = __builtin_amdgcn_exp2f(g[2]);
        const float eo = __builtin_amdgcn_exp2f(g[3]);
        const float A   = 1.0f + ei;     // 1/i
        const float F   = 1.0f + ef;     // 1/f
        const float G1  = eg + 1.0f;
        const float Gm  = eg - 1.0f;     // g = Gm/G1
        const float AG  = A * G1;
        const float num = fmaf(cst[qq], AG, Gm * F);
        const float cn  = num * __builtin_amdgcn_rcpf(F * AG);
        cst[qq] = cn;
        const float ec = __builtin_amdgcn_exp2f(TWOLOG2E * cn);
        const float hv = (ec - 1.0f) *
                         __builtin_amdgcn_rcpf((1.0f + eo) * (ec + 1.0f)); // o*tanh(c)
        if (wen[qq]) {
          _Float16* wpc = nxt ? wp1[qq] : wp0[qq];
          *wpc = (_Float16)hv;
        }
      }
    }
    if (is_x && t < 1023) hbuf[nxt][b][151] = xv;  // x_{t+1}
    __syncthreads();
    cur = nxt;
  }
}

extern "C" void kernel_launch(void* const* d_in, const int* in_sizes, int n_in,
                              void* d_out, int out_size, void* d_ws, size_t ws_size,
                              hipStream_t stream) {
  const float* x     = (const float*)d_in[0];
  const float* W_ih  = (const float*)d_in[1];
  const float* W_hh  = (const float*)d_in[2];
  const float* b_ih  = (const float*)d_in[3];
  const float* b_hh  = (const float*)d_in[4];
  const float* W_out = (const float*)d_in[5];
  const float* b_out = (const float*)d_in[6];
  lstm_kernel<<<dim3(128), dim3(512), 0, stream>>>(
      x, W_ih, W_hh, b_ih, b_hh, W_out, b_out, (float*)d_out);
}